// Round 8
// baseline (346.698 us; speedup 1.0000x reference)
//
#include <hip/hip_runtime.h>

#define BN_EPS 1e-3f

typedef __attribute__((ext_vector_type(8))) short bf16x8;
typedef __attribute__((ext_vector_type(16))) float floatx16;
typedef unsigned short u16;

__device__ __forceinline__ u16 f2bf(float f) {
  unsigned u = __float_as_uint(f);
  u += 0x7fffu + ((u >> 16) & 1u);   // RNE
  return (u16)(u >> 16);
}
__device__ __forceinline__ float bf2f(u16 h) {
  return __uint_as_float(((unsigned)h) << 16);
}

static constexpr int NSHARD = 64;   // stats shards (128 floats each)

// ---------------------------------------------------------------------------
// conv1_stats: per-channel sum/sumsq of relu(conv1(x)) -> sharded stats.
// NO y1 materialization.  Thread = (pixel slot ps, 4-ch group cg); 36 weights
// in registers; xp stride 36 (float4-aligned rows, conflict-free).
// ---------------------------------------------------------------------------
__global__ __launch_bounds__(256) void conv1_stats_k(
    const float* __restrict__ x, const float* __restrict__ k1,
    float* __restrict__ statsSh)
{
  __shared__ float xp[30 * 36];
  __shared__ float w1s[576];
  __shared__ float redsum[64], redss[64];

  const int be = blockIdx.x, b = be >> 6, tid = threadIdx.x;

  for (int i = tid; i < 1080; i += 256) xp[i] = 0.f;
  for (int i = tid; i < 576; i += 256) w1s[i] = k1[(size_t)b * 576 + i];
  if (tid < 64) { redsum[tid] = 0.f; redss[tid] = 0.f; }
  __syncthreads();
  for (int i = tid; i < 784; i += 256) {
    const int r = i / 28, c = i - 28 * r;
    xp[(r + 1) * 36 + (c + 1)] = x[(size_t)be * 784 + i];
  }
  __syncthreads();

  const int cg = (tid & 15) * 4, ps = tid >> 4;
  float wreg[4][9];
#pragma unroll
  for (int cc = 0; cc < 4; ++cc)
#pragma unroll
    for (int t = 0; t < 9; ++t) wreg[cc][t] = w1s[t * 64 + cg + cc];

  float sum[4] = {0.f, 0.f, 0.f, 0.f}, ss[4] = {0.f, 0.f, 0.f, 0.f};
  for (int p = ps; p < 196; p += 16) {
    const int iy = p / 14, ix = p - 14 * iy;
    const float* xb = &xp[(2 * iy) * 36 + 2 * ix];
    float xv[9];
#pragma unroll
    for (int ky = 0; ky < 3; ++ky)
#pragma unroll
      for (int kx = 0; kx < 3; ++kx) xv[ky * 3 + kx] = xb[ky * 36 + kx];
#pragma unroll
    for (int cc = 0; cc < 4; ++cc) {
      float a = 0.f;
#pragma unroll
      for (int t = 0; t < 9; ++t) a = fmaf(xv[t], wreg[cc][t], a);
      const float v = fmaxf(a, 0.f);
      sum[cc] += v;
      ss[cc] = fmaf(v, v, ss[cc]);
    }
  }
#pragma unroll
  for (int cc = 0; cc < 4; ++cc) {
    atomicAdd(&redsum[cg + cc], sum[cc]);
    atomicAdd(&redss[cg + cc], ss[cc]);
  }
  __syncthreads();
  if (tid < 64) {
    const int sh = be & (NSHARD - 1);
    atomicAdd(&statsSh[sh * 128 + tid], redsum[tid]);
    atomicAdd(&statsSh[sh * 128 + 64 + tid], redss[tid]);
  }
}

// ---------------------------------------------------------------------------
// fold: block (task, slice-triple).  Reduce stats shards -> s,t; emit
// Wf bf16 [b][s][cout][cin] scaled by s_cin; accumulate 9-class boundary
// bias table bias[b][cls][cout] (zeroed by memset).
// ---------------------------------------------------------------------------
__global__ __launch_bounds__(256) void foldw_k(
    const float* __restrict__ W, const float* __restrict__ statsSh, float invN,
    u16* __restrict__ Wf, float* __restrict__ biasCls)
{
  __shared__ float T[64 * 68];
  __shared__ float P[256];
  __shared__ float s1[64], t1[64];
  __shared__ float tbS[64];

  const int b = blockIdx.x / 3, sg = blockIdx.x % 3;
  const int tid = threadIdx.x;

  {
    const int g = tid >> 7, cidx = tid & 127;
    float acc = 0.f;
    for (int k = 0; k < NSHARD / 2; ++k)
      acc += statsSh[(g * (NSHARD / 2) + k) * 128 + cidx];
    P[tid] = acc;
  }
  __syncthreads();
  if (tid < 64) {
    const float m = (P[tid] + P[tid + 128]) * invN;
    const float var = fmaf(-m, m, (P[64 + tid] + P[192 + tid]) * invN);
    const float s = rsqrtf(var + BN_EPS);
    s1[tid] = s;
    t1[tid] = -m * s;
  }
  __syncthreads();

  const int cin = tid >> 2, q0 = (tid & 3) * 16;
  const int cout = tid >> 2, ci0 = (tid & 3) * 16;
  for (int s = sg * 3; s < sg * 3 + 3; ++s) {
    if (tid < 64) tbS[tid] = 0.f;
    const float* ss = W + ((size_t)b * 9 + s) * 4096;
#pragma unroll
    for (int q = 0; q < 16; q += 4) {
      const float4 v = *(const float4*)(ss + cin * 64 + q0 + q);
      T[(q0 + q + 0) * 68 + cin] = v.x;
      T[(q0 + q + 1) * 68 + cin] = v.y;
      T[(q0 + q + 2) * 68 + cin] = v.z;
      T[(q0 + q + 3) * 68 + cin] = v.w;
    }
    __syncthreads();
    alignas(16) u16 tmp[16];
    float tb = 0.f;
#pragma unroll
    for (int j = 0; j < 16; ++j) {
      const float wv = T[cout * 68 + ci0 + j];
      tmp[j] = f2bf(wv * s1[ci0 + j]);
      tb = fmaf(t1[ci0 + j], wv, tb);
    }
    u16* dst = Wf + ((size_t)b * 9 + s) * 4096 + cout * 64 + ci0;
    *(uint4*)dst       = *(uint4*)&tmp[0];
    *(uint4*)(dst + 8) = *(uint4*)&tmp[8];
    atomicAdd(&tbS[cout], tb);
    __syncthreads();
    if (tid < 64) {
      const int ky = s / 3, kx = s % 3;
      const float tv = tbS[tid];
#pragma unroll
      for (int cls = 0; cls < 9; ++cls) {
        const int ry = cls / 3, rx = cls % 3;
        const bool valid = !((ry == 1 && ky == 0) || (ry == 2 && ky == 2) ||
                             (rx == 1 && kx == 0) || (rx == 2 && kx == 2));
        if (valid) atomicAdd(&biasCls[(size_t)b * 576 + cls * 64 + tid], tv);
      }
    }
    __syncthreads();
  }
}

// ---------------------------------------------------------------------------
// cg2f: FUSED conv1+conv2, one block per image.  Phase A: build raw
// relu(conv1(x)) 196x64 bf16 map in LDS (36 weight regs/thread).  Phase B:
// round-6 GEMM vs k2f (BN1 folded in), B double-buffered in the SAME LDS
// region xp/w1s used (overlay).  y2 bf16 + sharded stats.
// ---------------------------------------------------------------------------
__global__ __launch_bounds__(256) void cg2f_k(
    const float* __restrict__ x, const float* __restrict__ k1,
    const u16* __restrict__ k2f, const float* __restrict__ biasCls,
    u16* __restrict__ y2, float* __restrict__ statsSh)
{
  __shared__ __align__(16) u16 mapS[197 * 72];   // 28368 B; row 196 = zeros
  __shared__ __align__(16) char ov[2 * 8704];    // overlay: {xp,w1s} / Bb[2]
  __shared__ float biasS[576];
  __shared__ float redsum[64], redss[64];

  float* xp  = (float*)ov;          // 30*36 floats = 4320 B
  float* w1s = xp + 1080;           // 576 floats   = 2304 B
  u16* Bb0 = (u16*)ov;              // 64*68 u16 = 8704 B
  u16* Bb1 = (u16*)(ov + 8704);

  const int be = blockIdx.x, b = be >> 6, tid = threadIdx.x;
  const int lane = tid & 63, wave = tid >> 6;

  for (int i = tid; i < 1080; i += 256) xp[i] = 0.f;
  for (int i = tid; i < 576; i += 256) w1s[i] = k1[(size_t)b * 576 + i];
  for (int i = tid; i < 576; i += 256) biasS[i] = biasCls[(size_t)b * 576 + i];
  if (tid < 64) { redsum[tid] = 0.f; redss[tid] = 0.f; }
  if (tid < 8) *(uint4*)&mapS[196 * 72 + tid * 8] = uint4{0, 0, 0, 0};
  __syncthreads();
  for (int i = tid; i < 784; i += 256) {
    const int r = i / 28, c = i - 28 * r;
    xp[(r + 1) * 36 + (c + 1)] = x[(size_t)be * 784 + i];
  }
  __syncthreads();

  // ---- phase A: build map (raw relu(conv1)) ----
  {
    const int cg = (tid & 15) * 4, ps = tid >> 4;
    float wreg[4][9];
#pragma unroll
    for (int cc = 0; cc < 4; ++cc)
#pragma unroll
      for (int t = 0; t < 9; ++t) wreg[cc][t] = w1s[t * 64 + cg + cc];

    for (int p = ps; p < 196; p += 16) {
      const int iy = p / 14, ix = p - 14 * iy;
      const float* xb = &xp[(2 * iy) * 36 + 2 * ix];
      float xv[9];
#pragma unroll
      for (int ky = 0; ky < 3; ++ky)
#pragma unroll
        for (int kx = 0; kx < 3; ++kx) xv[ky * 3 + kx] = xb[ky * 36 + kx];
      alignas(8) u16 o[4];
#pragma unroll
      for (int cc = 0; cc < 4; ++cc) {
        float a = 0.f;
#pragma unroll
        for (int t = 0; t < 9; ++t) a = fmaf(xv[t], wreg[cc][t], a);
        o[cc] = f2bf(fmaxf(a, 0.f));
      }
      *(uint2*)&mapS[p * 72 + cg] = *(uint2*)o;
    }
  }
  __syncthreads();   // map done; xp/w1s dead -> overlay becomes Bb

  // ---- phase B: GEMM 64(rows,49 valid) x 64 couts, K = 9 x 64 ----
  const int bco = tid >> 2, bci = (tid & 3) * 16;
  const u16* wb = k2f + (size_t)b * 9 * 4096 + bco * 64 + bci;
  {
    uint4 b0 = *(const uint4*)wb;
    uint4 b1 = *(const uint4*)(wb + 8);
    *(uint4*)&Bb0[bco * 68 + bci]     = b0;
    *(uint4*)&Bb0[bco * 68 + bci + 8] = b1;
  }

  const int m0 = (wave & 1) * 32, n0 = (wave >> 1) * 32;
  const int l31 = lane & 31, kq = (lane >> 5) * 8;
  const int lrow = m0 + l31;
  const bool rv = lrow < 49;
  const int oy = rv ? lrow / 7 : 0, ox = rv ? lrow % 7 : 0;

  floatx16 acc;
#pragma unroll
  for (int r = 0; r < 16; ++r) acc[r] = 0.f;

  __syncthreads();   // Bb0 ready

#pragma unroll
  for (int s = 0; s < 9; ++s) {
    uint4 nb0, nb1;
    if (s < 8) {
      const u16* wsl = wb + (s + 1) * 4096;
      nb0 = *(const uint4*)wsl;
      nb1 = *(const uint4*)(wsl + 8);
    }
    const int ky = s / 3, kx = s % 3;
    int pix = 196;
    if (rv) {
      const int iy = 2 * oy - 1 + ky, ix = 2 * ox - 1 + kx;
      if ((unsigned)iy < 14u && (unsigned)ix < 14u) pix = iy * 14 + ix;
    }
    const u16* ap = &mapS[pix * 72 + kq];
    const u16* bp = (s & 1) ? &Bb1[(n0 + l31) * 68 + kq]
                            : &Bb0[(n0 + l31) * 68 + kq];
#pragma unroll
    for (int kk = 0; kk < 4; ++kk) {
      bf16x8 a  = *(const bf16x8*)(ap + kk * 16);
      bf16x8 bv = *(const bf16x8*)(bp + kk * 16);
      acc = __builtin_amdgcn_mfma_f32_32x32x16_bf16(a, bv, acc, 0, 0, 0);
    }
    if (s < 8) {
      u16* d = ((s + 1) & 1) ? &Bb1[bco * 68 + bci] : &Bb0[bco * 68 + bci];
      *(uint4*)d       = nb0;
      *(uint4*)(d + 8) = nb1;
    }
    __syncthreads();
  }

  // epilogue
  const int col = n0 + l31;
  const int rb = m0 + 4 * (lane >> 5);
  float ls = 0.f, lss = 0.f;
#pragma unroll
  for (int r = 0; r < 16; ++r) {
    const int rw = rb + (r & 3) + 8 * (r >> 2);
    if (rw < 49) {
      const int ooy = rw / 7, oox = rw % 7;
      const int ry = (ooy == 0) ? 1 : 0;             // Hin=14 even: no bottom clip
      const int rx = (oox == 0) ? 1 : 0;
      const float v = fmaxf(acc[r] + biasS[(ry * 3 + rx) * 64 + col], 0.f);
      y2[((size_t)be * 49 + rw) * 64 + col] = f2bf(v);
      ls += v;
      lss = fmaf(v, v, lss);
    }
  }
  atomicAdd(&redsum[col], ls);
  atomicAdd(&redss[col], lss);
  __syncthreads();
  if (tid < 64) {
    const int sh = be & (NSHARD - 1);
    atomicAdd(&statsSh[sh * 128 + tid], redsum[tid]);
    atomicAdd(&statsSh[sh * 128 + 64 + tid], redss[tid]);
  }
}

// ---------------------------------------------------------------------------
// conv_core: layers 3..4.  G input images staged ONCE in LDS; B double-
// buffered; M=64 x N=64, 4 waves, 1 acc/wave 32x32x16 bf16 MFMA.
// ---------------------------------------------------------------------------
template <int Hin, int Hout, int G>
__device__ __forceinline__ void conv_core(
    const u16* __restrict__ yin, const u16* __restrict__ Wf,
    const float* __restrict__ biasCls, u16* __restrict__ yout,
    float* __restrict__ statsSh, int blk)
{
  constexpr int PPI  = Hout * Hout;
  constexpr int ROWS = G * PPI;          // <= 64
  constexpr int BPT  = 64 / G;
  constexpr int MR   = G * Hin * Hin;
  constexpr int ZR   = MR;

  __shared__ __align__(16) u16 mapS[(MR + 1) * 72];
  __shared__ __align__(16) u16 Bb[2][64 * 72];
  __shared__ float biasS[576];
  __shared__ float redsum[64], redss[64];

  const int b = blk / BPT, e0 = (blk % BPT) * G;
  const int tid = threadIdx.x, lane = tid & 63, wave = tid >> 6;

  for (int i = tid; i < 576; i += 256) biasS[i] = biasCls[(size_t)b * 576 + i];
  if (tid < 64) { redsum[tid] = 0.f; redss[tid] = 0.f; }
  if (tid < 8) *(uint4*)&mapS[ZR * 72 + tid * 8] = uint4{0, 0, 0, 0};

  {
    const u16* src = yin + (size_t)(b * 64 + e0) * (Hin * Hin) * 64;
    for (int ch = tid; ch < MR * 8; ch += 256) {
      const int r = ch >> 3, c8 = ch & 7;
      *(uint4*)&mapS[r * 72 + c8 * 8] = *(const uint4*)(src + ch * 8);
    }
  }

  const int bco = tid >> 2, bci = (tid & 3) * 16;
  const u16* wb = Wf + (size_t)b * 9 * 4096 + bco * 64 + bci;
  {
    uint4 b0 = *(const uint4*)wb;
    uint4 b1 = *(const uint4*)(wb + 8);
    *(uint4*)&Bb[0][bco * 72 + bci]     = b0;
    *(uint4*)&Bb[0][bco * 72 + bci + 8] = b1;
  }

  const int m0 = (wave & 1) * 32, n0 = (wave >> 1) * 32;
  const int l31 = lane & 31, kq = (lane >> 5) * 8;
  const int lrow = m0 + l31;
  const bool rv = lrow < ROWS;
  const int img = rv ? lrow / PPI : 0;
  const int pp  = rv ? lrow % PPI : 0;
  const int oy = pp / Hout, ox = pp % Hout;

  floatx16 acc;
#pragma unroll
  for (int r = 0; r < 16; ++r) acc[r] = 0.f;

  __syncthreads();

#pragma unroll
  for (int s = 0; s < 9; ++s) {
    uint4 nb0, nb1;
    if (s < 8) {
      const u16* wsl = wb + (s + 1) * 4096;
      nb0 = *(const uint4*)wsl;
      nb1 = *(const uint4*)(wsl + 8);
    }
    const int ky = s / 3, kx = s % 3;
    int pix = ZR;
    if (rv) {
      const int iy = 2 * oy - 1 + ky, ix = 2 * ox - 1 + kx;
      if ((unsigned)iy < (unsigned)Hin && (unsigned)ix < (unsigned)Hin)
        pix = img * (Hin * Hin) + iy * Hin + ix;
    }
    const u16* ap = &mapS[pix * 72 + kq];
    const u16* bp = &Bb[s & 1][(n0 + l31) * 72 + kq];
#pragma unroll
    for (int kk = 0; kk < 4; ++kk) {
      bf16x8 a  = *(const bf16x8*)(ap + kk * 16);
      bf16x8 bv = *(const bf16x8*)(bp + kk * 16);
      acc = __builtin_amdgcn_mfma_f32_32x32x16_bf16(a, bv, acc, 0, 0, 0);
    }
    if (s < 8) {
      u16* d = &Bb[(s + 1) & 1][bco * 72 + bci];
      *(uint4*)d       = nb0;
      *(uint4*)(d + 8) = nb1;
    }
    __syncthreads();
  }

  const int col = n0 + l31;
  const int rb = m0 + 4 * (lane >> 5);
  float ls = 0.f, lss = 0.f;
#pragma unroll
  for (int r = 0; r < 16; ++r) {
    const int rw = rb + (r & 3) + 8 * (r >> 2);
    if (rw < ROWS) {
      const int re = rw / PPI, pr = rw % PPI;
      const int ooy = pr / Hout, oox = pr % Hout;
      const int ry = (ooy == 0) ? 1 : ((2 * ooy + 1 >= Hin) ? 2 : 0);
      const int rx = (oox == 0) ? 1 : ((2 * oox + 1 >= Hin) ? 2 : 0);
      const float v = fmaxf(acc[r] + biasS[(ry * 3 + rx) * 64 + col], 0.f);
      yout[((size_t)(b * 64 + e0 + re) * PPI + pr) * 64 + col] = f2bf(v);
      ls += v;
      lss = fmaf(v, v, lss);
    }
  }
  atomicAdd(&redsum[col], ls);
  atomicAdd(&redss[col], lss);
  __syncthreads();
  if (tid < 64) {
    const int sh = blk & (NSHARD - 1);
    atomicAdd(&statsSh[sh * 128 + tid], redsum[tid]);
    atomicAdd(&statsSh[sh * 128 + 64 + tid], redss[tid]);
  }
}

__global__ __launch_bounds__(256) void cg3_k(
    const u16* __restrict__ yin, const u16* __restrict__ Wf,
    const float* __restrict__ biasCls, u16* __restrict__ yout,
    float* __restrict__ statsSh) {
  conv_core<7, 4, 4>(yin, Wf, biasCls, yout, statsSh, blockIdx.x);
}
__global__ __launch_bounds__(256) void cg4_k(
    const u16* __restrict__ yin, const u16* __restrict__ Wf,
    const float* __restrict__ biasCls, u16* __restrict__ yout,
    float* __restrict__ statsSh) {
  conv_core<4, 2, 16>(yin, Wf, biasCls, yout, statsSh, blockIdx.x);
}

// ---------------------------------------------------------------------------
// readout: reduce stats4 shards, feat = BN(maxpool(y4)), out = feat @ w_ro[b].
// ---------------------------------------------------------------------------
__global__ __launch_bounds__(256) void readout_k(
    const u16* __restrict__ y4, const float* __restrict__ w_ro,
    const float* __restrict__ statsSh, float invN, float* __restrict__ outp)
{
  __shared__ float wl[64 * 20];
  __shared__ float feat[64 * 64];
  __shared__ float P[256];
  __shared__ float sArr[64], tArr[64];

  const int b = blockIdx.x, tid = threadIdx.x;

  {
    const int g = tid >> 7, cidx = tid & 127;
    float acc = 0.f;
    for (int k = 0; k < NSHARD / 2; ++k)
      acc += statsSh[(g * (NSHARD / 2) + k) * 128 + cidx];
    P[tid] = acc;
  }
  for (int i = tid; i < 1280; i += 256) wl[i] = w_ro[(size_t)b * 1280 + i];
  __syncthreads();
  if (tid < 64) {
    const float m = (P[tid] + P[tid + 128]) * invN;
    const float var = fmaf(-m, m, (P[64 + tid] + P[192 + tid]) * invN);
    const float s = rsqrtf(var + BN_EPS);
    sArr[tid] = s;
    tArr[tid] = -m * s;
  }
  __syncthreads();

  {
    const int e = tid & 63;
    for (int c = tid >> 6; c < 64; c += 4) {
      const u16* p4 = y4 + ((size_t)(b * 64 + e) * 4) * 64 + c;
      const float v = fmaxf(fmaxf(bf2f(p4[0]), bf2f(p4[64])),
                            fmaxf(bf2f(p4[128]), bf2f(p4[192])));
      feat[c * 64 + e] = fmaf(v, sArr[c], tArr[c]);
    }
  }
  __syncthreads();

  const int e = tid >> 2, og = (tid & 3) * 5;
  float acc[5] = {0.f, 0.f, 0.f, 0.f, 0.f};
  for (int c = 0; c < 64; ++c) {
    const float f = feat[c * 64 + e];
#pragma unroll
    for (int j = 0; j < 5; ++j) acc[j] = fmaf(f, wl[c * 20 + og + j], acc[j]);
  }
#pragma unroll
  for (int j = 0; j < 5; ++j)
    outp[((size_t)b * 64 + e) * 20 + og + j] = acc[j];
}

// ---------------------------------------------------------------------------
extern "C" void kernel_launch(void* const* d_in, const int* in_sizes, int n_in,
                              void* d_out, int out_size, void* d_ws, size_t ws_size,
                              hipStream_t stream) {
  (void)in_sizes; (void)n_in; (void)out_size; (void)ws_size;
  const float* x   = (const float*)d_in[0];
  const float* k1  = (const float*)d_in[1];
  const float* k2  = (const float*)d_in[2];
  const float* k3  = (const float*)d_in[3];
  const float* k4  = (const float*)d_in[4];
  const float* wro = (const float*)d_in[5];
  float* out = (float*)d_out;
  char* ws = (char*)d_ws;

  // ws layout (bytes), total ~51 MB (y1 eliminated):
  //  stats: 4 layers x 64 shards x 128 f32         = 131072
  //  bias2/3/4: 64 x 576 f32                       = 3 x 147456 (memset w/ stats)
  //  k2f/k3f/k4f bf16                              = 3 x 4718592
  //  y2 bf16 [4096][49][64]                        = 25690112
  //  y3 bf16 [4096][16][64]                        = 8388608
  //  y4 bf16 [4096][4][64]                         = 2097152
  float* stats = (float*)ws;
  float* bias2 = (float*)(ws + 131072);
  float* bias3 = bias2 + 36864;
  float* bias4 = bias3 + 36864;
  u16* k2f = (u16*)(ws + 131072 + 442368);
  u16* k3f = k2f + (size_t)2359296;
  u16* k4f = k3f + (size_t)2359296;
  u16* y2 = k4f + (size_t)2359296;
  u16* y3 = y2 + (size_t)12845056;
  u16* y4 = y3 + (size_t)4194304;

  float* st1 = stats;
  float* st2 = stats + 8192;
  float* st3 = stats + 16384;
  float* st4 = stats + 24576;

  hipMemsetAsync(stats, 0, 131072 + 442368, stream);

  conv1_stats_k<<<4096, 256, 0, stream>>>(x, k1, st1);
  foldw_k<<<192, 256, 0, stream>>>(k2, st1, 1.f / 802816.f, k2f, bias2);
  cg2f_k<<<4096, 256, 0, stream>>>(x, k1, k2f, bias2, y2, st2);
  foldw_k<<<192, 256, 0, stream>>>(k3, st2, 1.f / 200704.f, k3f, bias3);
  cg3_k<<<1024, 256, 0, stream>>>(y2, k3f, bias3, y3, st3);
  foldw_k<<<192, 256, 0, stream>>>(k4, st3, 1.f / 65536.f, k4f, bias4);
  cg4_k<<<256, 256, 0, stream>>>(y3, k4f, bias4, y4, st4);
  readout_k<<<64, 256, 0, stream>>>(y4, wro, st4, 1.f / 16384.f, out);
}

// Round 9
// 296.000 us; speedup vs baseline: 1.1713x; 1.1713x over previous
//
#include <hip/hip_runtime.h>

#define BN_EPS 1e-3f

typedef __attribute__((ext_vector_type(8))) short bf16x8;
typedef __attribute__((ext_vector_type(16))) float floatx16;
typedef unsigned short u16;

__device__ __forceinline__ u16 f2bf(float f) {
  unsigned u = __float_as_uint(f);
  u += 0x7fffu + ((u >> 16) & 1u);   // RNE
  return (u16)(u >> 16);
}
__device__ __forceinline__ float bf2f(u16 h) {
  return __uint_as_float(((unsigned)h) << 16);
}

static constexpr int NSHARD = 64;   // stats shards (128 floats each)

// ---------------------------------------------------------------------------
// conv1_stats: per-channel sum/sumsq of relu(conv1(x)) -> sharded stats.
// No y1 materialization.  6.6 KB LDS -> high occupancy.
// ---------------------------------------------------------------------------
__global__ __launch_bounds__(256) void conv1_stats_k(
    const float* __restrict__ x, const float* __restrict__ k1,
    float* __restrict__ statsSh)
{
  __shared__ float xp[30 * 36];
  __shared__ float w1s[576];
  __shared__ float redsum[64], redss[64];

  const int be = blockIdx.x, b = be >> 6, tid = threadIdx.x;

  for (int i = tid; i < 1080; i += 256) xp[i] = 0.f;
  for (int i = tid; i < 576; i += 256) w1s[i] = k1[(size_t)b * 576 + i];
  if (tid < 64) { redsum[tid] = 0.f; redss[tid] = 0.f; }
  __syncthreads();
  for (int i = tid; i < 784; i += 256) {
    const int r = i / 28, c = i - 28 * r;
    xp[(r + 1) * 36 + (c + 1)] = x[(size_t)be * 784 + i];
  }
  __syncthreads();

  const int cg = (tid & 15) * 4, ps = tid >> 4;
  float wreg[4][9];
#pragma unroll
  for (int cc = 0; cc < 4; ++cc)
#pragma unroll
    for (int t = 0; t < 9; ++t) wreg[cc][t] = w1s[t * 64 + cg + cc];

  float sum[4] = {0.f, 0.f, 0.f, 0.f}, ss[4] = {0.f, 0.f, 0.f, 0.f};
  for (int p = ps; p < 196; p += 16) {
    const int iy = p / 14, ix = p - 14 * iy;
    const float* xb = &xp[(2 * iy) * 36 + 2 * ix];
    float xv[9];
#pragma unroll
    for (int ky = 0; ky < 3; ++ky)
#pragma unroll
      for (int kx = 0; kx < 3; ++kx) xv[ky * 3 + kx] = xb[ky * 36 + kx];
#pragma unroll
    for (int cc = 0; cc < 4; ++cc) {
      float a = 0.f;
#pragma unroll
      for (int t = 0; t < 9; ++t) a = fmaf(xv[t], wreg[cc][t], a);
      const float v = fmaxf(a, 0.f);
      sum[cc] += v;
      ss[cc] = fmaf(v, v, ss[cc]);
    }
  }
#pragma unroll
  for (int cc = 0; cc < 4; ++cc) {
    atomicAdd(&redsum[cg + cc], sum[cc]);
    atomicAdd(&redss[cg + cc], ss[cc]);
  }
  __syncthreads();
  if (tid < 64) {
    const int sh = be & (NSHARD - 1);
    atomicAdd(&statsSh[sh * 128 + tid], redsum[tid]);
    atomicAdd(&statsSh[sh * 128 + 64 + tid], redss[tid]);
  }
}

// ---------------------------------------------------------------------------
// fold: block (task, slice-triple).  Reduce stats shards -> s,t; emit
// Wf bf16 [b][s][cout][cin] scaled by s_cin; accumulate 9-class boundary
// bias table bias[b][cls][cout] (zeroed by memset).
// ---------------------------------------------------------------------------
__global__ __launch_bounds__(256) void foldw_k(
    const float* __restrict__ W, const float* __restrict__ statsSh, float invN,
    u16* __restrict__ Wf, float* __restrict__ biasCls)
{
  __shared__ float T[64 * 68];
  __shared__ float P[256];
  __shared__ float s1[64], t1[64];
  __shared__ float tbS[64];

  const int b = blockIdx.x / 3, sg = blockIdx.x % 3;
  const int tid = threadIdx.x;

  {
    const int g = tid >> 7, cidx = tid & 127;
    float acc = 0.f;
    for (int k = 0; k < NSHARD / 2; ++k)
      acc += statsSh[(g * (NSHARD / 2) + k) * 128 + cidx];
    P[tid] = acc;
  }
  __syncthreads();
  if (tid < 64) {
    const float m = (P[tid] + P[tid + 128]) * invN;
    const float var = fmaf(-m, m, (P[64 + tid] + P[192 + tid]) * invN);
    const float s = rsqrtf(var + BN_EPS);
    s1[tid] = s;
    t1[tid] = -m * s;
  }
  __syncthreads();

  const int cin = tid >> 2, q0 = (tid & 3) * 16;
  const int cout = tid >> 2, ci0 = (tid & 3) * 16;
  for (int s = sg * 3; s < sg * 3 + 3; ++s) {
    if (tid < 64) tbS[tid] = 0.f;
    const float* ss = W + ((size_t)b * 9 + s) * 4096;
#pragma unroll
    for (int q = 0; q < 16; q += 4) {
      const float4 v = *(const float4*)(ss + cin * 64 + q0 + q);
      T[(q0 + q + 0) * 68 + cin] = v.x;
      T[(q0 + q + 1) * 68 + cin] = v.y;
      T[(q0 + q + 2) * 68 + cin] = v.z;
      T[(q0 + q + 3) * 68 + cin] = v.w;
    }
    __syncthreads();
    alignas(16) u16 tmp[16];
    float tb = 0.f;
#pragma unroll
    for (int j = 0; j < 16; ++j) {
      const float wv = T[cout * 68 + ci0 + j];
      tmp[j] = f2bf(wv * s1[ci0 + j]);
      tb = fmaf(t1[ci0 + j], wv, tb);
    }
    u16* dst = Wf + ((size_t)b * 9 + s) * 4096 + cout * 64 + ci0;
    *(uint4*)dst       = *(uint4*)&tmp[0];
    *(uint4*)(dst + 8) = *(uint4*)&tmp[8];
    atomicAdd(&tbS[cout], tb);
    __syncthreads();
    if (tid < 64) {
      const int ky = s / 3, kx = s % 3;
      const float tv = tbS[tid];
#pragma unroll
      for (int cls = 0; cls < 9; ++cls) {
        const int ry = cls / 3, rx = cls % 3;
        const bool valid = !((ry == 1 && ky == 0) || (ry == 2 && ky == 2) ||
                             (rx == 1 && kx == 0) || (rx == 2 && kx == 2));
        if (valid) atomicAdd(&biasCls[(size_t)b * 576 + cls * 64 + tid], tv);
      }
    }
    __syncthreads();
  }
}

// ---------------------------------------------------------------------------
// cg2f: FUSED conv1+conv2, one block per image.  Phase A builds the raw
// relu(conv1(x)) 196x64 bf16 map in LDS.  Phase B: implicit GEMM with
// B-fragments loaded DIRECTLY FROM GLOBAL (k2f is L2-resident, task-shared)
// -> no Bb LDS, NO K-loop barriers.  LDS ~38 KB -> 4 blocks/CU.
// ---------------------------------------------------------------------------
__global__ __launch_bounds__(256) void cg2f_k(
    const float* __restrict__ x, const float* __restrict__ k1,
    const u16* __restrict__ k2f, const float* __restrict__ biasCls,
    u16* __restrict__ y2, float* __restrict__ statsSh)
{
  __shared__ __align__(16) u16 mapS[197 * 72];   // 28368 B; row 196 = zeros
  __shared__ float xp[30 * 36];
  __shared__ float w1s[576];
  __shared__ float biasS[576];
  __shared__ float redsum[64], redss[64];

  const int be = blockIdx.x, b = be >> 6, tid = threadIdx.x;
  const int lane = tid & 63, wave = tid >> 6;

  for (int i = tid; i < 1080; i += 256) xp[i] = 0.f;
  for (int i = tid; i < 576; i += 256) w1s[i] = k1[(size_t)b * 576 + i];
  for (int i = tid; i < 576; i += 256) biasS[i] = biasCls[(size_t)b * 576 + i];
  if (tid < 64) { redsum[tid] = 0.f; redss[tid] = 0.f; }
  if (tid < 8) *(uint4*)&mapS[196 * 72 + tid * 8] = uint4{0, 0, 0, 0};
  __syncthreads();
  for (int i = tid; i < 784; i += 256) {
    const int r = i / 28, c = i - 28 * r;
    xp[(r + 1) * 36 + (c + 1)] = x[(size_t)be * 784 + i];
  }
  __syncthreads();

  // ---- phase A: build map (raw relu(conv1)) ----
  {
    const int cg = (tid & 15) * 4, ps = tid >> 4;
    float wreg[4][9];
#pragma unroll
    for (int cc = 0; cc < 4; ++cc)
#pragma unroll
      for (int t = 0; t < 9; ++t) wreg[cc][t] = w1s[t * 64 + cg + cc];

    for (int p = ps; p < 196; p += 16) {
      const int iy = p / 14, ix = p - 14 * iy;
      const float* xb = &xp[(2 * iy) * 36 + 2 * ix];
      float xv[9];
#pragma unroll
      for (int ky = 0; ky < 3; ++ky)
#pragma unroll
        for (int kx = 0; kx < 3; ++kx) xv[ky * 3 + kx] = xb[ky * 36 + kx];
      alignas(8) u16 o[4];
#pragma unroll
      for (int cc = 0; cc < 4; ++cc) {
        float a = 0.f;
#pragma unroll
        for (int t = 0; t < 9; ++t) a = fmaf(xv[t], wreg[cc][t], a);
        o[cc] = f2bf(fmaxf(a, 0.f));
      }
      *(uint2*)&mapS[p * 72 + cg] = *(uint2*)o;
    }
  }
  __syncthreads();   // map ready — last block-wide sync before epilogue

  // ---- phase B: 36 MFMAs, A from LDS map, B from global (L2) ----
  const int m0 = (wave & 1) * 32, n0 = (wave >> 1) * 32;
  const int l31 = lane & 31, kq = (lane >> 5) * 8;
  const int lrow = m0 + l31;
  const bool rv = lrow < 49;
  const int oy = rv ? lrow / 7 : 0, ox = rv ? lrow % 7 : 0;
  const u16* wbB = k2f + (size_t)b * 9 * 4096 + (n0 + l31) * 64 + kq;

  floatx16 acc;
#pragma unroll
  for (int r = 0; r < 16; ++r) acc[r] = 0.f;

#pragma unroll
  for (int s = 0; s < 9; ++s) {
    const int ky = s / 3, kx = s % 3;
    int pix = 196;
    if (rv) {
      const int iy = 2 * oy - 1 + ky, ix = 2 * ox - 1 + kx;
      if ((unsigned)iy < 14u && (unsigned)ix < 14u) pix = iy * 14 + ix;
    }
    const u16* ap = &mapS[pix * 72 + kq];
    const u16* bp = wbB + s * 4096;
#pragma unroll
    for (int kk = 0; kk < 4; ++kk) {
      bf16x8 a  = *(const bf16x8*)(ap + kk * 16);
      bf16x8 bv = *(const bf16x8*)(bp + kk * 16);
      acc = __builtin_amdgcn_mfma_f32_32x32x16_bf16(a, bv, acc, 0, 0, 0);
    }
  }

  // epilogue
  const int col = n0 + l31;
  const int rb = m0 + 4 * (lane >> 5);
  float ls = 0.f, lss = 0.f;
#pragma unroll
  for (int r = 0; r < 16; ++r) {
    const int rw = rb + (r & 3) + 8 * (r >> 2);
    if (rw < 49) {
      const int ooy = rw / 7, oox = rw % 7;
      const int ry = (ooy == 0) ? 1 : 0;   // Hin=14 even: no bottom clip
      const int rx = (oox == 0) ? 1 : 0;
      const float v = fmaxf(acc[r] + biasS[(ry * 3 + rx) * 64 + col], 0.f);
      y2[((size_t)be * 49 + rw) * 64 + col] = f2bf(v);
      ls += v;
      lss = fmaf(v, v, lss);
    }
  }
  atomicAdd(&redsum[col], ls);
  atomicAdd(&redss[col], lss);
  __syncthreads();
  if (tid < 64) {
    const int sh = be & (NSHARD - 1);
    atomicAdd(&statsSh[sh * 128 + tid], redsum[tid]);
    atomicAdd(&statsSh[sh * 128 + 64 + tid], redss[tid]);
  }
}

// ---------------------------------------------------------------------------
// conv_core: layers 3..4.  G input images staged ONCE in LDS; B-fragments
// from global (no Bb LDS, no K-loop barriers).  M=64 x N=64, 4 waves.
// ---------------------------------------------------------------------------
template <int Hin, int Hout, int G>
__device__ __forceinline__ void conv_core(
    const u16* __restrict__ yin, const u16* __restrict__ Wf,
    const float* __restrict__ biasCls, u16* __restrict__ yout,
    float* __restrict__ statsSh, int blk)
{
  constexpr int PPI  = Hout * Hout;
  constexpr int ROWS = G * PPI;          // <= 64
  constexpr int BPT  = 64 / G;
  constexpr int MR   = G * Hin * Hin;
  constexpr int ZR   = MR;

  __shared__ __align__(16) u16 mapS[(MR + 1) * 72];
  __shared__ float biasS[576];
  __shared__ float redsum[64], redss[64];

  const int b = blk / BPT, e0 = (blk % BPT) * G;
  const int tid = threadIdx.x, lane = tid & 63, wave = tid >> 6;

  for (int i = tid; i < 576; i += 256) biasS[i] = biasCls[(size_t)b * 576 + i];
  if (tid < 64) { redsum[tid] = 0.f; redss[tid] = 0.f; }
  if (tid < 8) *(uint4*)&mapS[ZR * 72 + tid * 8] = uint4{0, 0, 0, 0};

  {
    const u16* src = yin + (size_t)(b * 64 + e0) * (Hin * Hin) * 64;
    for (int ch = tid; ch < MR * 8; ch += 256) {
      const int r = ch >> 3, c8 = ch & 7;
      *(uint4*)&mapS[r * 72 + c8 * 8] = *(const uint4*)(src + ch * 8);
    }
  }

  const int m0 = (wave & 1) * 32, n0 = (wave >> 1) * 32;
  const int l31 = lane & 31, kq = (lane >> 5) * 8;
  const int lrow = m0 + l31;
  const bool rv = lrow < ROWS;
  const int img = rv ? lrow / PPI : 0;
  const int pp  = rv ? lrow % PPI : 0;
  const int oy = pp / Hout, ox = pp % Hout;
  const u16* wbB = Wf + (size_t)b * 9 * 4096 + (n0 + l31) * 64 + kq;

  floatx16 acc;
#pragma unroll
  for (int r = 0; r < 16; ++r) acc[r] = 0.f;

  __syncthreads();   // map ready

#pragma unroll
  for (int s = 0; s < 9; ++s) {
    const int ky = s / 3, kx = s % 3;
    int pix = ZR;
    if (rv) {
      const int iy = 2 * oy - 1 + ky, ix = 2 * ox - 1 + kx;
      if ((unsigned)iy < (unsigned)Hin && (unsigned)ix < (unsigned)Hin)
        pix = img * (Hin * Hin) + iy * Hin + ix;
    }
    const u16* ap = &mapS[pix * 72 + kq];
    const u16* bp = wbB + s * 4096;
#pragma unroll
    for (int kk = 0; kk < 4; ++kk) {
      bf16x8 a  = *(const bf16x8*)(ap + kk * 16);
      bf16x8 bv = *(const bf16x8*)(bp + kk * 16);
      acc = __builtin_amdgcn_mfma_f32_32x32x16_bf16(a, bv, acc, 0, 0, 0);
    }
  }

  const int col = n0 + l31;
  const int rb = m0 + 4 * (lane >> 5);
  float ls = 0.f, lss = 0.f;
#pragma unroll
  for (int r = 0; r < 16; ++r) {
    const int rw = rb + (r & 3) + 8 * (r >> 2);
    if (rw < ROWS) {
      const int re = rw / PPI, pr = rw % PPI;
      const int ooy = pr / Hout, oox = pr % Hout;
      const int ry = (ooy == 0) ? 1 : ((2 * ooy + 1 >= Hin) ? 2 : 0);
      const int rx = (oox == 0) ? 1 : ((2 * oox + 1 >= Hin) ? 2 : 0);
      const float v = fmaxf(acc[r] + biasS[(ry * 3 + rx) * 64 + col], 0.f);
      yout[((size_t)(b * 64 + e0 + re) * PPI + pr) * 64 + col] = f2bf(v);
      ls += v;
      lss = fmaf(v, v, lss);
    }
  }
  atomicAdd(&redsum[col], ls);
  atomicAdd(&redss[col], lss);
  __syncthreads();
  if (tid < 64) {
    const int sh = blk & (NSHARD - 1);
    atomicAdd(&statsSh[sh * 128 + tid], redsum[tid]);
    atomicAdd(&statsSh[sh * 128 + 64 + tid], redss[tid]);
  }
}

__global__ __launch_bounds__(256) void cg3_k(
    const u16* __restrict__ yin, const u16* __restrict__ Wf,
    const float* __restrict__ biasCls, u16* __restrict__ yout,
    float* __restrict__ statsSh) {
  conv_core<7, 4, 4>(yin, Wf, biasCls, yout, statsSh, blockIdx.x);
}
__global__ __launch_bounds__(256) void cg4_k(
    const u16* __restrict__ yin, const u16* __restrict__ Wf,
    const float* __restrict__ biasCls, u16* __restrict__ yout,
    float* __restrict__ statsSh) {
  conv_core<4, 2, 16>(yin, Wf, biasCls, yout, statsSh, blockIdx.x);
}

// ---------------------------------------------------------------------------
// readout: reduce stats4 shards, feat = BN(maxpool(y4)), out = feat @ w_ro[b].
// ---------------------------------------------------------------------------
__global__ __launch_bounds__(256) void readout_k(
    const u16* __restrict__ y4, const float* __restrict__ w_ro,
    const float* __restrict__ statsSh, float invN, float* __restrict__ outp)
{
  __shared__ float wl[64 * 20];
  __shared__ float feat[64 * 64];
  __shared__ float P[256];
  __shared__ float sArr[64], tArr[64];

  const int b = blockIdx.x, tid = threadIdx.x;

  {
    const int g = tid >> 7, cidx = tid & 127;
    float acc = 0.f;
    for (int k = 0; k < NSHARD / 2; ++k)
      acc += statsSh[(g * (NSHARD / 2) + k) * 128 + cidx];
    P[tid] = acc;
  }
  for (int i = tid; i < 1280; i += 256) wl[i] = w_ro[(size_t)b * 1280 + i];
  __syncthreads();
  if (tid < 64) {
    const float m = (P[tid] + P[tid + 128]) * invN;
    const float var = fmaf(-m, m, (P[64 + tid] + P[192 + tid]) * invN);
    const float s = rsqrtf(var + BN_EPS);
    sArr[tid] = s;
    tArr[tid] = -m * s;
  }
  __syncthreads();

  {
    const int e = tid & 63;
    for (int c = tid >> 6; c < 64; c += 4) {
      const u16* p4 = y4 + ((size_t)(b * 64 + e) * 4) * 64 + c;
      const float v = fmaxf(fmaxf(bf2f(p4[0]), bf2f(p4[64])),
                            fmaxf(bf2f(p4[128]), bf2f(p4[192])));
      feat[c * 64 + e] = fmaf(v, sArr[c], tArr[c]);
    }
  }
  __syncthreads();

  const int e = tid >> 2, og = (tid & 3) * 5;
  float acc[5] = {0.f, 0.f, 0.f, 0.f, 0.f};
  for (int c = 0; c < 64; ++c) {
    const float f = feat[c * 64 + e];
#pragma unroll
    for (int j = 0; j < 5; ++j) acc[j] = fmaf(f, wl[c * 20 + og + j], acc[j]);
  }
#pragma unroll
  for (int j = 0; j < 5; ++j)
    outp[((size_t)b * 64 + e) * 20 + og + j] = acc[j];
}

// ---------------------------------------------------------------------------
extern "C" void kernel_launch(void* const* d_in, const int* in_sizes, int n_in,
                              void* d_out, int out_size, void* d_ws, size_t ws_size,
                              hipStream_t stream) {
  (void)in_sizes; (void)n_in; (void)out_size; (void)ws_size;
  const float* x   = (const float*)d_in[0];
  const float* k1  = (const float*)d_in[1];
  const float* k2  = (const float*)d_in[2];
  const float* k3  = (const float*)d_in[3];
  const float* k4  = (const float*)d_in[4];
  const float* wro = (const float*)d_in[5];
  float* out = (float*)d_out;
  char* ws = (char*)d_ws;

  // ws layout (bytes), total ~51 MB:
  //  stats: 4 layers x 64 shards x 128 f32         = 131072
  //  bias2/3/4: 64 x 576 f32                       = 3 x 147456 (memset w/ stats)
  //  k2f/k3f/k4f bf16                              = 3 x 4718592
  //  y2 / y3 / y4 bf16                             = 25690112 / 8388608 / 2097152
  float* stats = (float*)ws;
  float* bias2 = (float*)(ws + 131072);
  float* bias3 = bias2 + 36864;
  float* bias4 = bias3 + 36864;
  u16* k2f = (u16*)(ws + 131072 + 442368);
  u16* k3f = k2f + (size_t)2359296;
  u16* k4f = k3f + (size_t)2359296;
  u16* y2 = k4f + (size_t)2359296;
  u16* y3 = y2 + (size_t)12845056;
  u16* y4 = y3 + (size_t)4194304;

  float* st1 = stats;
  float* st2 = stats + 8192;
  float* st3 = stats + 16384;
  float* st4 = stats + 24576;

  hipMemsetAsync(stats, 0, 131072 + 442368, stream);

  conv1_stats_k<<<4096, 256, 0, stream>>>(x, k1, st1);
  foldw_k<<<192, 256, 0, stream>>>(k2, st1, 1.f / 802816.f, k2f, bias2);
  cg2f_k<<<4096, 256, 0, stream>>>(x, k1, k2f, bias2, y2, st2);
  foldw_k<<<192, 256, 0, stream>>>(k3, st2, 1.f / 200704.f, k3f, bias3);
  cg3_k<<<1024, 256, 0, stream>>>(y2, k3f, bias3, y3, st3);
  foldw_k<<<192, 256, 0, stream>>>(k4, st3, 1.f / 65536.f, k4f, bias4);
  cg4_k<<<256, 256, 0, stream>>>(y3, k4f, bias4, y4, st4);
  readout_k<<<64, 256, 0, stream>>>(y4, wro, st4, 1.f / 16384.f, out);
}

// Round 10
// 275.886 us; speedup vs baseline: 1.2567x; 1.0729x over previous
//
#include <hip/hip_runtime.h>

#define BN_EPS 1e-3f

typedef __attribute__((ext_vector_type(8))) short bf16x8;
typedef __attribute__((ext_vector_type(16))) float floatx16;
typedef unsigned short u16;

__device__ __forceinline__ u16 f2bf(float f) {
  unsigned u = __float_as_uint(f);
  u += 0x7fffu + ((u >> 16) & 1u);   // RNE
  return (u16)(u >> 16);
}
__device__ __forceinline__ float bf2f(u16 h) {
  return __uint_as_float(((unsigned)h) << 16);
}

static constexpr int NSHARD = 64;   // stats shards (128 floats each)

// ---------------------------------------------------------------------------
// prep: k2/k3/k4 fp32 [b][s][cin][cout] -> PLAIN bf16 transposed
// [b][s][cout][cin] (no BN).  192 blocks = 3 layers x 64 tasks.
// ---------------------------------------------------------------------------
__global__ __launch_bounds__(256) void prep_k(
    const float* __restrict__ k2, const float* __restrict__ k3,
    const float* __restrict__ k4, u16* __restrict__ k2T,
    u16* __restrict__ k3T, u16* __restrict__ k4T)
{
  __shared__ float T[64 * 68];
  const int blk = blockIdx.x, l = blk >> 6, b = blk & 63;
  const float* src = (l == 0 ? k2 : l == 1 ? k3 : k4) + (size_t)b * 9 * 4096;
  u16* dst = (l == 0 ? k2T : l == 1 ? k3T : k4T) + (size_t)b * 9 * 4096;
  const int tid = threadIdx.x;
  const int cin = tid >> 2, q0 = (tid & 3) * 16;
  const int cout = tid >> 2, ci0 = (tid & 3) * 16;

  for (int s = 0; s < 9; ++s) {
    const float* ss = src + s * 4096;
#pragma unroll
    for (int q = 0; q < 16; q += 4) {
      const float4 v = *(const float4*)(ss + cin * 64 + q0 + q);
      T[(q0 + q + 0) * 68 + cin] = v.x;
      T[(q0 + q + 1) * 68 + cin] = v.y;
      T[(q0 + q + 2) * 68 + cin] = v.z;
      T[(q0 + q + 3) * 68 + cin] = v.w;
    }
    __syncthreads();
    alignas(16) u16 tmp[16];
#pragma unroll
    for (int j = 0; j < 16; ++j) tmp[j] = f2bf(T[cout * 68 + ci0 + j]);
    u16* d = dst + s * 4096 + cout * 64 + ci0;
    *(uint4*)d       = *(uint4*)&tmp[0];
    *(uint4*)(d + 8) = *(uint4*)&tmp[8];
    __syncthreads();
  }
}

// ---------------------------------------------------------------------------
// conv1s: stats of relu(conv1(x)) via MFMA (A=196x16 patches, B=w1 16x64).
// 2 MFMAs per 32-pixel tile instead of 441 scalar FMAs/thread.
// ---------------------------------------------------------------------------
__global__ __launch_bounds__(256) void conv1s_k(
    const float* __restrict__ x, const float* __restrict__ k1,
    float* __restrict__ statsSh)
{
  __shared__ float xp[30 * 36];   // padded input, zero border
  __shared__ float w1s[576];
  __shared__ float redsum[64], redss[64];

  const int be = blockIdx.x, b = be >> 6, tid = threadIdx.x;
  const int lane = tid & 63, wave = tid >> 6;
  const int l31 = lane & 31, kq8 = (lane >> 5) * 8;

  for (int i = tid; i < 1080; i += 256) xp[i] = 0.f;
  for (int i = tid; i < 576; i += 256) w1s[i] = k1[(size_t)b * 576 + i];
  if (tid < 64) { redsum[tid] = 0.f; redss[tid] = 0.f; }
  __syncthreads();
  for (int i = tid; i < 784; i += 256) {
    const int r = i / 28, c = i - 28 * r;
    xp[(r + 1) * 36 + (c + 1)] = x[(size_t)be * 784 + i];
  }
  __syncthreads();

  bf16x8 bf0, bf1;
#pragma unroll
  for (int j = 0; j < 8; ++j) {
    const int k = kq8 + j;
    bf0[j] = (k < 9) ? (short)f2bf(w1s[k * 64 + l31]) : (short)0;
    bf1[j] = (k < 9) ? (short)f2bf(w1s[k * 64 + 32 + l31]) : (short)0;
  }

  float s0 = 0.f, q0 = 0.f, s1v = 0.f, q1 = 0.f;
  for (int t = wave; t < 7; t += 4) {
    const int row = t * 32 + l31;
    const int p = row < 196 ? row : 195;
    const int oy = p / 14, ox = p - 14 * oy;
    bf16x8 af;
#pragma unroll
    for (int j = 0; j < 8; ++j) {
      const int k = kq8 + j;
      float v = 0.f;
      if (k < 9) v = xp[(2 * oy + k / 3) * 36 + (2 * ox + k % 3)];
      af[j] = (short)f2bf(v);
    }
    floatx16 z;
#pragma unroll
    for (int r = 0; r < 16; ++r) z[r] = 0.f;
    floatx16 c0 = __builtin_amdgcn_mfma_f32_32x32x16_bf16(af, bf0, z, 0, 0, 0);
    floatx16 c1 = __builtin_amdgcn_mfma_f32_32x32x16_bf16(af, bf1, z, 0, 0, 0);
    const int rb = t * 32 + 4 * (lane >> 5);
#pragma unroll
    for (int r = 0; r < 16; ++r) {
      const int rw = rb + (r & 3) + 8 * (r >> 2);
      if (rw < 196) {
        const float v0 = fmaxf(c0[r], 0.f), v1 = fmaxf(c1[r], 0.f);
        s0 += v0; q0 = fmaf(v0, v0, q0);
        s1v += v1; q1 = fmaf(v1, v1, q1);
      }
    }
  }
  atomicAdd(&redsum[l31], s0);
  atomicAdd(&redss[l31], q0);
  atomicAdd(&redsum[32 + l31], s1v);
  atomicAdd(&redss[32 + l31], q1);
  __syncthreads();
  if (tid < 64) {
    const int sh = be & (NSHARD - 1);
    atomicAdd(&statsSh[sh * 128 + tid], redsum[tid]);
    atomicAdd(&statsSh[sh * 128 + 64 + tid], redss[tid]);
  }
}

// ---------------------------------------------------------------------------
// cg2f: fused conv1+conv2.  Prologue: reduce st1 -> BN1 (s,t).  Phase A:
// conv1 via MFMA, BN1 folded into C-regs, bf16 map (225 rows; 196 valid +
// dupes + zero-row 224).  Phase B: implicit GEMM vs plain k2T from global,
// plain ReLU epilogue (zero-row = exact reference zero-padding).
// ---------------------------------------------------------------------------
__global__ __launch_bounds__(256) void cg2f_k(
    const float* __restrict__ x, const float* __restrict__ k1,
    const u16* __restrict__ k2T, const float* __restrict__ statsPrev,
    float invN, u16* __restrict__ y2, float* __restrict__ statsSh)
{
  __shared__ __align__(16) u16 mapS[225 * 72];   // 32400 B
  __shared__ float xp[30 * 36];
  __shared__ float w1s[576];
  __shared__ float P[256];
  __shared__ float s1[64], t1[64];
  __shared__ float redsum[64], redss[64];

  const int be = blockIdx.x, b = be >> 6, tid = threadIdx.x;
  const int lane = tid & 63, wave = tid >> 6;
  const int l31 = lane & 31, kq8 = (lane >> 5) * 8;

  for (int i = tid; i < 1080; i += 256) xp[i] = 0.f;
  for (int i = tid; i < 576; i += 256) w1s[i] = k1[(size_t)b * 576 + i];
  if (tid < 64) { redsum[tid] = 0.f; redss[tid] = 0.f; }
  if (tid < 9) *(uint4*)&mapS[224 * 72 + tid * 8] = uint4{0, 0, 0, 0};
  {
    const int cidx = tid & 127, g = tid >> 7;
    float a = 0.f;
    for (int k = 0; k < NSHARD / 2; ++k)
      a += statsPrev[(g * (NSHARD / 2) + k) * 128 + cidx];
    P[tid] = a;
  }
  __syncthreads();
  if (tid < 64) {
    const float m = (P[tid] + P[tid + 128]) * invN;
    const float var = fmaf(-m, m, (P[64 + tid] + P[192 + tid]) * invN);
    const float s = rsqrtf(var + BN_EPS);
    s1[tid] = s;
    t1[tid] = -m * s;
  }
  for (int i = tid; i < 784; i += 256) {
    const int r = i / 28, c = i - 28 * r;
    xp[(r + 1) * 36 + (c + 1)] = x[(size_t)be * 784 + i];
  }
  __syncthreads();

  // ---- phase A: conv1 MFMA + BN1 -> map ----
  {
    bf16x8 bf0, bf1;
#pragma unroll
    for (int j = 0; j < 8; ++j) {
      const int k = kq8 + j;
      bf0[j] = (k < 9) ? (short)f2bf(w1s[k * 64 + l31]) : (short)0;
      bf1[j] = (k < 9) ? (short)f2bf(w1s[k * 64 + 32 + l31]) : (short)0;
    }
    const float sc0 = s1[l31], tc0 = t1[l31];
    const float sc1 = s1[32 + l31], tc1 = t1[32 + l31];
    for (int t = wave; t < 7; t += 4) {
      const int row = t * 32 + l31;
      const int p = row < 196 ? row : 195;
      const int oy = p / 14, ox = p - 14 * oy;
      bf16x8 af;
#pragma unroll
      for (int j = 0; j < 8; ++j) {
        const int k = kq8 + j;
        float v = 0.f;
        if (k < 9) v = xp[(2 * oy + k / 3) * 36 + (2 * ox + k % 3)];
        af[j] = (short)f2bf(v);
      }
      floatx16 z;
#pragma unroll
      for (int r = 0; r < 16; ++r) z[r] = 0.f;
      floatx16 c0 = __builtin_amdgcn_mfma_f32_32x32x16_bf16(af, bf0, z, 0, 0, 0);
      floatx16 c1 = __builtin_amdgcn_mfma_f32_32x32x16_bf16(af, bf1, z, 0, 0, 0);
      const int rb = t * 32 + 4 * (lane >> 5);
#pragma unroll
      for (int r = 0; r < 16; ++r) {
        const int rw = rb + (r & 3) + 8 * (r >> 2);
        mapS[rw * 72 + l31]      = f2bf(fmaf(fmaxf(c0[r], 0.f), sc0, tc0));
        mapS[rw * 72 + 32 + l31] = f2bf(fmaf(fmaxf(c1[r], 0.f), sc1, tc1));
      }
    }
  }
  __syncthreads();

  // ---- phase B: 36 MFMAs; A from map, B from global (L2) ----
  const int m0 = (wave & 1) * 32, n0 = (wave >> 1) * 32;
  const int lrow = m0 + l31;
  const bool rv = lrow < 49;
  const int oy = rv ? lrow / 7 : 0, ox = rv ? lrow % 7 : 0;
  const u16* wbB = k2T + (size_t)b * 9 * 4096 + (n0 + l31) * 64 + kq8;

  floatx16 acc;
#pragma unroll
  for (int r = 0; r < 16; ++r) acc[r] = 0.f;

#pragma unroll
  for (int s = 0; s < 9; ++s) {
    const int ky = s / 3, kx = s % 3;
    int pix = 224;
    if (rv) {
      const int iy = 2 * oy - 1 + ky, ix = 2 * ox - 1 + kx;
      if ((unsigned)iy < 14u && (unsigned)ix < 14u) pix = iy * 14 + ix;
    }
    const u16* ap = &mapS[pix * 72 + kq8];
    const u16* bp = wbB + s * 4096;
#pragma unroll
    for (int kk = 0; kk < 4; ++kk) {
      bf16x8 a  = *(const bf16x8*)(ap + kk * 16);
      bf16x8 bv = *(const bf16x8*)(bp + kk * 16);
      acc = __builtin_amdgcn_mfma_f32_32x32x16_bf16(a, bv, acc, 0, 0, 0);
    }
  }

  const int col = n0 + l31;
  const int rb = m0 + 4 * (lane >> 5);
  float ls = 0.f, lss = 0.f;
#pragma unroll
  for (int r = 0; r < 16; ++r) {
    const int rw = rb + (r & 3) + 8 * (r >> 2);
    if (rw < 49) {
      const float v = fmaxf(acc[r], 0.f);
      y2[((size_t)be * 49 + rw) * 64 + col] = f2bf(v);
      ls += v;
      lss = fmaf(v, v, lss);
    }
  }
  atomicAdd(&redsum[col], ls);
  atomicAdd(&redss[col], lss);
  __syncthreads();
  if (tid < 64) {
    const int sh = be & (NSHARD - 1);
    atomicAdd(&statsSh[sh * 128 + tid], redsum[tid]);
    atomicAdd(&statsSh[sh * 128 + 64 + tid], redss[tid]);
  }
}

// ---------------------------------------------------------------------------
// conv_core_bn: layers 3..4.  Prologue: reduce prev stats -> (s,t).  Staging:
// BN applied to map values (zero-row stays zero = exact ref padding).
// Phase B: B from global, plain ReLU epilogue, sharded stats.
// ---------------------------------------------------------------------------
template <int Hin, int Hout, int G>
__device__ __forceinline__ void conv_core_bn(
    const u16* __restrict__ yin, const u16* __restrict__ wT,
    const float* __restrict__ statsPrev, float invN, u16* __restrict__ yout,
    float* __restrict__ statsSh, int blk)
{
  constexpr int PPI  = Hout * Hout;
  constexpr int ROWS = G * PPI;          // <= 64
  constexpr int BPT  = 64 / G;
  constexpr int MR   = G * Hin * Hin;
  constexpr int ZR   = MR;

  __shared__ __align__(16) u16 mapS[(MR + 1) * 72];
  __shared__ float P[256];
  __shared__ float s1[64], t1[64];
  __shared__ float redsum[64], redss[64];

  const int b = blk / BPT, e0 = (blk % BPT) * G;
  const int tid = threadIdx.x, lane = tid & 63, wave = tid >> 6;

  if (tid < 64) { redsum[tid] = 0.f; redss[tid] = 0.f; }
  if (tid < 9) *(uint4*)&mapS[ZR * 72 + tid * 8] = uint4{0, 0, 0, 0};
  {
    const int cidx = tid & 127, g = tid >> 7;
    float a = 0.f;
    for (int k = 0; k < NSHARD / 2; ++k)
      a += statsPrev[(g * (NSHARD / 2) + k) * 128 + cidx];
    P[tid] = a;
  }
  __syncthreads();
  if (tid < 64) {
    const float m = (P[tid] + P[tid + 128]) * invN;
    const float var = fmaf(-m, m, (P[64 + tid] + P[192 + tid]) * invN);
    const float s = rsqrtf(var + BN_EPS);
    s1[tid] = s;
    t1[tid] = -m * s;
  }
  __syncthreads();

  // staging with BN affine folded in
  {
    const u16* src = yin + (size_t)(b * 64 + e0) * (Hin * Hin) * 64;
    for (int ch = tid; ch < MR * 8; ch += 256) {
      const int r = ch >> 3, c0 = (ch & 7) * 8;
      uint4 v = *(const uint4*)(src + ch * 8);
      const u16* h = (const u16*)&v;
      alignas(16) u16 o[8];
#pragma unroll
      for (int j = 0; j < 8; ++j)
        o[j] = f2bf(fmaf(bf2f(h[j]), s1[c0 + j], t1[c0 + j]));
      *(uint4*)&mapS[r * 72 + c0] = *(uint4*)o;
    }
  }

  const int m0 = (wave & 1) * 32, n0 = (wave >> 1) * 32;
  const int l31 = lane & 31, kq8 = (lane >> 5) * 8;
  const int lrow = m0 + l31;
  const bool rv = lrow < ROWS;
  const int img = rv ? lrow / PPI : 0;
  const int pp  = rv ? lrow % PPI : 0;
  const int oy = pp / Hout, ox = pp % Hout;
  const u16* wbB = wT + (size_t)b * 9 * 4096 + (n0 + l31) * 64 + kq8;

  floatx16 acc;
#pragma unroll
  for (int r = 0; r < 16; ++r) acc[r] = 0.f;

  __syncthreads();   // map ready

#pragma unroll
  for (int s = 0; s < 9; ++s) {
    const int ky = s / 3, kx = s % 3;
    int pix = ZR;
    if (rv) {
      const int iy = 2 * oy - 1 + ky, ix = 2 * ox - 1 + kx;
      if ((unsigned)iy < (unsigned)Hin && (unsigned)ix < (unsigned)Hin)
        pix = img * (Hin * Hin) + iy * Hin + ix;
    }
    const u16* ap = &mapS[pix * 72 + kq8];
    const u16* bp = wbB + s * 4096;
#pragma unroll
    for (int kk = 0; kk < 4; ++kk) {
      bf16x8 a  = *(const bf16x8*)(ap + kk * 16);
      bf16x8 bv = *(const bf16x8*)(bp + kk * 16);
      acc = __builtin_amdgcn_mfma_f32_32x32x16_bf16(a, bv, acc, 0, 0, 0);
    }
  }

  const int col = n0 + l31;
  const int rb = m0 + 4 * (lane >> 5);
  float ls = 0.f, lss = 0.f;
#pragma unroll
  for (int r = 0; r < 16; ++r) {
    const int rw = rb + (r & 3) + 8 * (r >> 2);
    if (rw < ROWS) {
      const int re = rw / PPI, pr = rw % PPI;
      const float v = fmaxf(acc[r], 0.f);
      yout[((size_t)(b * 64 + e0 + re) * PPI + pr) * 64 + col] = f2bf(v);
      ls += v;
      lss = fmaf(v, v, lss);
    }
  }
  atomicAdd(&redsum[col], ls);
  atomicAdd(&redss[col], lss);
  __syncthreads();
  if (tid < 64) {
    const int sh = blk & (NSHARD - 1);
    atomicAdd(&statsSh[sh * 128 + tid], redsum[tid]);
    atomicAdd(&statsSh[sh * 128 + 64 + tid], redss[tid]);
  }
}

__global__ __launch_bounds__(256) void cg3_k(
    const u16* __restrict__ yin, const u16* __restrict__ wT,
    const float* __restrict__ stPrev, float invN, u16* __restrict__ yout,
    float* __restrict__ statsSh) {
  conv_core_bn<7, 4, 4>(yin, wT, stPrev, invN, yout, statsSh, blockIdx.x);
}
__global__ __launch_bounds__(256) void cg4_k(
    const u16* __restrict__ yin, const u16* __restrict__ wT,
    const float* __restrict__ stPrev, float invN, u16* __restrict__ yout,
    float* __restrict__ statsSh) {
  conv_core_bn<4, 2, 16>(yin, wT, stPrev, invN, yout, statsSh, blockIdx.x);
}

// ---------------------------------------------------------------------------
// readout: reduce st4 shards, feat = BN(maxpool(y4)), out = feat @ w_ro[b].
// ---------------------------------------------------------------------------
__global__ __launch_bounds__(256) void readout_k(
    const u16* __restrict__ y4, const float* __restrict__ w_ro,
    const float* __restrict__ statsSh, float invN, float* __restrict__ outp)
{
  __shared__ float wl[64 * 20];
  __shared__ float feat[64 * 64];
  __shared__ float P[256];
  __shared__ float sArr[64], tArr[64];

  const int b = blockIdx.x, tid = threadIdx.x;

  {
    const int g = tid >> 7, cidx = tid & 127;
    float acc = 0.f;
    for (int k = 0; k < NSHARD / 2; ++k)
      acc += statsSh[(g * (NSHARD / 2) + k) * 128 + cidx];
    P[tid] = acc;
  }
  for (int i = tid; i < 1280; i += 256) wl[i] = w_ro[(size_t)b * 1280 + i];
  __syncthreads();
  if (tid < 64) {
    const float m = (P[tid] + P[tid + 128]) * invN;
    const float var = fmaf(-m, m, (P[64 + tid] + P[192 + tid]) * invN);
    const float s = rsqrtf(var + BN_EPS);
    sArr[tid] = s;
    tArr[tid] = -m * s;
  }
  __syncthreads();

  {
    const int e = tid & 63;
    for (int c = tid >> 6; c < 64; c += 4) {
      const u16* p4 = y4 + ((size_t)(b * 64 + e) * 4) * 64 + c;
      const float v = fmaxf(fmaxf(bf2f(p4[0]), bf2f(p4[64])),
                            fmaxf(bf2f(p4[128]), bf2f(p4[192])));
      feat[c * 64 + e] = fmaf(v, sArr[c], tArr[c]);
    }
  }
  __syncthreads();

  const int e = tid >> 2, og = (tid & 3) * 5;
  float acc[5] = {0.f, 0.f, 0.f, 0.f, 0.f};
  for (int c = 0; c < 64; ++c) {
    const float f = feat[c * 64 + e];
#pragma unroll
    for (int j = 0; j < 5; ++j) acc[j] = fmaf(f, wl[c * 20 + og + j], acc[j]);
  }
#pragma unroll
  for (int j = 0; j < 5; ++j)
    outp[((size_t)b * 64 + e) * 20 + og + j] = acc[j];
}

// ---------------------------------------------------------------------------
extern "C" void kernel_launch(void* const* d_in, const int* in_sizes, int n_in,
                              void* d_out, int out_size, void* d_ws, size_t ws_size,
                              hipStream_t stream) {
  (void)in_sizes; (void)n_in; (void)out_size; (void)ws_size;
  const float* x   = (const float*)d_in[0];
  const float* k1  = (const float*)d_in[1];
  const float* k2  = (const float*)d_in[2];
  const float* k3  = (const float*)d_in[3];
  const float* k4  = (const float*)d_in[4];
  const float* wro = (const float*)d_in[5];
  float* out = (float*)d_out;
  char* ws = (char*)d_ws;

  // ws layout (bytes), total ~50.5 MB (no bias tables):
  //  stats: 4 layers x 64 shards x 128 f32   = 131072
  //  k2T/k3T/k4T bf16                        = 3 x 4718592
  //  y2 / y3 / y4 bf16                       = 25690112 / 8388608 / 2097152
  float* stats = (float*)ws;
  u16* k2T = (u16*)(ws + 131072);
  u16* k3T = k2T + (size_t)2359296;
  u16* k4T = k3T + (size_t)2359296;
  u16* y2 = k4T + (size_t)2359296;
  u16* y3 = y2 + (size_t)12845056;
  u16* y4 = y3 + (size_t)4194304;

  float* st1 = stats;
  float* st2 = stats + 8192;
  float* st3 = stats + 16384;
  float* st4 = stats + 24576;

  hipMemsetAsync(stats, 0, 131072, stream);

  prep_k<<<192, 256, 0, stream>>>(k2, k3, k4, k2T, k3T, k4T);
  conv1s_k<<<4096, 256, 0, stream>>>(x, k1, st1);
  cg2f_k<<<4096, 256, 0, stream>>>(x, k1, k2T, st1, 1.f / 802816.f, y2, st2);
  cg3_k<<<1024, 256, 0, stream>>>(y2, k3T, st2, 1.f / 200704.f, y3, st3);
  cg4_k<<<256, 256, 0, stream>>>(y3, k4T, st3, 1.f / 65536.f, y4, st4);
  readout_k<<<64, 256, 0, stream>>>(y4, wro, st4, 1.f / 16384.f, out);
}

// Round 11
// 268.674 us; speedup vs baseline: 1.2904x; 1.0268x over previous
//
#include <hip/hip_runtime.h>

#define BN_EPS 1e-3f

typedef __attribute__((ext_vector_type(8))) short bf16x8;
typedef __attribute__((ext_vector_type(16))) float floatx16;
typedef unsigned short u16;

__device__ __forceinline__ u16 f2bf(float f) {
  unsigned u = __float_as_uint(f);
  u += 0x7fffu + ((u >> 16) & 1u);   // RNE
  return (u16)(u >> 16);
}
__device__ __forceinline__ float bf2f(u16 h) {
  return __uint_as_float(((unsigned)h) << 16);
}

static constexpr int NSHARD = 64;   // stats shards (128 floats each)

// ---------------------------------------------------------------------------
// c1_k: blocks 0..4095: conv1 via MFMA -> RAW y1 bf16 [be][196][64] + sharded
// stats.  Blocks 4096..4223: transpose k3/k4 fp32 -> bf16 [b][s][cout][cin].
// ---------------------------------------------------------------------------
__global__ __launch_bounds__(256) void c1_k(
    const float* __restrict__ x, const float* __restrict__ k1,
    const float* __restrict__ k3, const float* __restrict__ k4,
    u16* __restrict__ k3T, u16* __restrict__ k4T,
    u16* __restrict__ y1, float* __restrict__ statsSh)
{
  __shared__ __align__(16) char lds[17408];
  const int tid = threadIdx.x;

  if (blockIdx.x >= 4096) {           // ---- weight transpose part ----
    float* T = (float*)lds;           // 64 x 68
    const int blk = blockIdx.x - 4096, l = blk >> 6, b = blk & 63;
    const float* src = (l == 0 ? k3 : k4) + (size_t)b * 9 * 4096;
    u16* dst = (l == 0 ? k3T : k4T) + (size_t)b * 9 * 4096;
    const int cin = tid >> 2, q0 = (tid & 3) * 16;
    const int cout = tid >> 2, ci0 = (tid & 3) * 16;
    for (int s = 0; s < 9; ++s) {
      const float* ss = src + s * 4096;
#pragma unroll
      for (int q = 0; q < 16; q += 4) {
        const float4 v = *(const float4*)(ss + cin * 64 + q0 + q);
        T[(q0 + q + 0) * 68 + cin] = v.x;
        T[(q0 + q + 1) * 68 + cin] = v.y;
        T[(q0 + q + 2) * 68 + cin] = v.z;
        T[(q0 + q + 3) * 68 + cin] = v.w;
      }
      __syncthreads();
      alignas(16) u16 tmp[16];
#pragma unroll
      for (int j = 0; j < 16; ++j) tmp[j] = f2bf(T[cout * 68 + ci0 + j]);
      u16* d = dst + s * 4096 + cout * 64 + ci0;
      *(uint4*)d       = *(uint4*)&tmp[0];
      *(uint4*)(d + 8) = *(uint4*)&tmp[8];
      __syncthreads();
    }
    return;
  }

  // ---- conv1 part ----
  float* xp     = (float*)lds;            // 30*36 = 1080 floats (zero border)
  float* w1s    = (float*)(lds + 4320);   // 576
  float* redsum = (float*)(lds + 6624);   // 64
  float* redss  = (float*)(lds + 6880);   // 64

  const int be = blockIdx.x, b = be >> 6;
  const int lane = tid & 63, wave = tid >> 6;
  const int l31 = lane & 31, kq8 = (lane >> 5) * 8;

  for (int i = tid; i < 1080; i += 256) xp[i] = 0.f;
  for (int i = tid; i < 576; i += 256) w1s[i] = k1[(size_t)b * 576 + i];
  if (tid < 64) { redsum[tid] = 0.f; redss[tid] = 0.f; }
  __syncthreads();
  for (int i = tid; i < 784; i += 256) {
    const int r = i / 28, c = i - 28 * r;
    xp[(r + 1) * 36 + (c + 1)] = x[(size_t)be * 784 + i];
  }
  __syncthreads();

  bf16x8 bf0, bf1;
#pragma unroll
  for (int j = 0; j < 8; ++j) {
    const int k = kq8 + j;
    bf0[j] = (k < 9) ? (short)f2bf(w1s[k * 64 + l31]) : (short)0;
    bf1[j] = (k < 9) ? (short)f2bf(w1s[k * 64 + 32 + l31]) : (short)0;
  }

  float s0 = 0.f, q0v = 0.f, s1v = 0.f, q1v = 0.f;
  for (int t = wave; t < 7; t += 4) {
    const int row = t * 32 + l31;
    const int p = row < 196 ? row : 195;
    const int oy = p / 14, ox = p - 14 * oy;
    bf16x8 af;
#pragma unroll
    for (int j = 0; j < 8; ++j) {
      const int k = kq8 + j;
      float v = 0.f;
      if (k < 9) v = xp[(2 * oy + k / 3) * 36 + (2 * ox + k % 3)];
      af[j] = (short)f2bf(v);
    }
    floatx16 z;
#pragma unroll
    for (int r = 0; r < 16; ++r) z[r] = 0.f;
    floatx16 c0 = __builtin_amdgcn_mfma_f32_32x32x16_bf16(af, bf0, z, 0, 0, 0);
    floatx16 c1 = __builtin_amdgcn_mfma_f32_32x32x16_bf16(af, bf1, z, 0, 0, 0);
    const int rb = t * 32 + 4 * (lane >> 5);
#pragma unroll
    for (int r = 0; r < 16; ++r) {
      const int rw = rb + (r & 3) + 8 * (r >> 2);
      if (rw < 196) {
        const float v0 = fmaxf(c0[r], 0.f), v1 = fmaxf(c1[r], 0.f);
        const size_t ob = ((size_t)be * 196 + rw) * 64;
        y1[ob + l31]      = f2bf(v0);
        y1[ob + 32 + l31] = f2bf(v1);
        s0 += v0;  q0v = fmaf(v0, v0, q0v);
        s1v += v1; q1v = fmaf(v1, v1, q1v);
      }
    }
  }
  atomicAdd(&redsum[l31], s0);
  atomicAdd(&redss[l31], q0v);
  atomicAdd(&redsum[32 + l31], s1v);
  atomicAdd(&redss[32 + l31], q1v);
  __syncthreads();
  if (tid < 64) {
    const int sh = be & (NSHARD - 1);
    atomicAdd(&statsSh[sh * 128 + tid], redsum[tid]);
    atomicAdd(&statsSh[sh * 128 + 64 + tid], redss[tid]);
  }
}

// ---------------------------------------------------------------------------
// foldw: block (task, slice-triple).  Reduce stats shards -> s,t; emit
// Wf bf16 [b][s][cout][cin] scaled by s_cin; accumulate 9-class boundary
// bias table bias[b][cls][cout] (zeroed by memset).  [R6-proven]
// ---------------------------------------------------------------------------
__global__ __launch_bounds__(256) void foldw_k(
    const float* __restrict__ W, const float* __restrict__ statsSh, float invN,
    u16* __restrict__ Wf, float* __restrict__ biasCls)
{
  __shared__ float T[64 * 68];
  __shared__ float P[256];
  __shared__ float s1[64], t1[64];
  __shared__ float tbS[64];

  const int b = blockIdx.x / 3, sg = blockIdx.x % 3;
  const int tid = threadIdx.x;

  {
    const int g = tid >> 7, cidx = tid & 127;
    float acc = 0.f;
    for (int k = 0; k < NSHARD / 2; ++k)
      acc += statsSh[(g * (NSHARD / 2) + k) * 128 + cidx];
    P[tid] = acc;
  }
  __syncthreads();
  if (tid < 64) {
    const float m = (P[tid] + P[tid + 128]) * invN;
    const float var = fmaf(-m, m, (P[64 + tid] + P[192 + tid]) * invN);
    const float s = rsqrtf(var + BN_EPS);
    s1[tid] = s;
    t1[tid] = -m * s;
  }
  __syncthreads();

  const int cin = tid >> 2, q0 = (tid & 3) * 16;
  const int cout = tid >> 2, ci0 = (tid & 3) * 16;
  for (int s = sg * 3; s < sg * 3 + 3; ++s) {
    if (tid < 64) tbS[tid] = 0.f;
    const float* ss = W + ((size_t)b * 9 + s) * 4096;
#pragma unroll
    for (int q = 0; q < 16; q += 4) {
      const float4 v = *(const float4*)(ss + cin * 64 + q0 + q);
      T[(q0 + q + 0) * 68 + cin] = v.x;
      T[(q0 + q + 1) * 68 + cin] = v.y;
      T[(q0 + q + 2) * 68 + cin] = v.z;
      T[(q0 + q + 3) * 68 + cin] = v.w;
    }
    __syncthreads();
    alignas(16) u16 tmp[16];
    float tb = 0.f;
#pragma unroll
    for (int j = 0; j < 16; ++j) {
      const float wv = T[cout * 68 + ci0 + j];
      tmp[j] = f2bf(wv * s1[ci0 + j]);
      tb = fmaf(t1[ci0 + j], wv, tb);
    }
    u16* dst = Wf + ((size_t)b * 9 + s) * 4096 + cout * 64 + ci0;
    *(uint4*)dst       = *(uint4*)&tmp[0];
    *(uint4*)(dst + 8) = *(uint4*)&tmp[8];
    atomicAdd(&tbS[cout], tb);
    __syncthreads();
    if (tid < 64) {
      const int ky = s / 3, kx = s % 3;
      const float tv = tbS[tid];
#pragma unroll
      for (int cls = 0; cls < 9; ++cls) {
        const int ry = cls / 3, rx = cls % 3;
        const bool valid = !((ry == 1 && ky == 0) || (ry == 2 && ky == 2) ||
                             (rx == 1 && kx == 0) || (rx == 2 && kx == 2));
        if (valid) atomicAdd(&biasCls[(size_t)b * 576 + cls * 64 + tid], tv);
      }
    }
    __syncthreads();
  }
}

// ---------------------------------------------------------------------------
// cg2_k: conv2 as round-4's measured-best GEMM.  M=256 rows (4 images x 49,
// zero-padded), N=64, K=9x64.  Per-slice A staging (raw copy, coalesced:
// 8 lanes per 128B row), B in LDS, 4 waves x 2x2 acc = 16 MFMA/slice/wave.
// BN folded in k2f + bias-class epilogue.  bf16 out + sharded stats.
// ---------------------------------------------------------------------------
__global__ __launch_bounds__(256) void cg2_k(
    const u16* __restrict__ y1, const u16* __restrict__ k2f,
    const float* __restrict__ biasCls, u16* __restrict__ y2,
    float* __restrict__ statsSh)
{
  __shared__ __align__(16) u16 AS[256 * 72];   // 36,864 B
  __shared__ __align__(16) u16 BtS[64 * 72];   //  9,216 B
  __shared__ float biasS[576];
  __shared__ float redsum[64], redss[64];

  const int b = blockIdx.x >> 4, e0 = (blockIdx.x & 15) * 4;
  const int tid = threadIdx.x, lane = tid & 63, wave = tid >> 6;
  const int l31 = lane & 31, kq8 = (lane >> 5) * 8;

  for (int i = tid; i < 576; i += 256) biasS[i] = biasCls[(size_t)b * 576 + i];
  if (tid < 64) { redsum[tid] = 0.f; redss[tid] = 0.f; }
  for (int i = tid; i < 480; i += 256) {   // zero pad rows 196..255 once
    const int row = 196 + (i >> 3), c8 = (i & 7) * 8;
    *(uint4*)&AS[row * 72 + c8] = uint4{0, 0, 0, 0};
  }

  const size_t yb = (size_t)(b * 64 + e0) * 196 * 64;
  const u16* wb = k2f + (size_t)b * 9 * 4096;
  const int bco = tid >> 2, bci = (tid & 3) * 16;
  const int m0 = wave * 64;

  floatx16 acc00, acc01, acc10, acc11;
#pragma unroll
  for (int r = 0; r < 16; ++r) {
    acc00[r] = 0.f; acc01[r] = 0.f; acc10[r] = 0.f; acc11[r] = 0.f;
  }

  for (int s = 0; s < 9; ++s) {
    const int ky = s / 3, kx = s % 3;
    // stage A (rows 0..195): 8 lanes cover one 128B row -> coalesced
    for (int i = tid; i < 1568; i += 256) {
      const int row = i >> 3, c8 = (i & 7) * 8;
      const int e_l = row / 49, pp = row % 49;
      const int oy = pp / 7, ox = pp % 7;
      const int iy = 2 * oy - 1 + ky, ix = 2 * ox - 1 + kx;
      uint4 v = uint4{0, 0, 0, 0};
      if ((unsigned)iy < 14u && (unsigned)ix < 14u)
        v = *(const uint4*)(y1 + yb + ((size_t)e_l * 196 + iy * 14 + ix) * 64 + c8);
      *(uint4*)&AS[row * 72 + c8] = v;
    }
    // stage B
    {
      const u16* g = wb + s * 4096 + bco * 64 + bci;
      *(uint4*)&BtS[bco * 72 + bci]     = *(const uint4*)g;
      *(uint4*)&BtS[bco * 72 + bci + 8] = *(const uint4*)(g + 8);
    }
    __syncthreads();
#pragma unroll
    for (int kk = 0; kk < 4; ++kk) {
      const int ko = kk * 16 + kq8;
      bf16x8 a0 = *(const bf16x8*)&AS[(m0 + l31) * 72 + ko];
      bf16x8 a1 = *(const bf16x8*)&AS[(m0 + 32 + l31) * 72 + ko];
      bf16x8 b0 = *(const bf16x8*)&BtS[l31 * 72 + ko];
      bf16x8 b1 = *(const bf16x8*)&BtS[(32 + l31) * 72 + ko];
      acc00 = __builtin_amdgcn_mfma_f32_32x32x16_bf16(a0, b0, acc00, 0, 0, 0);
      acc01 = __builtin_amdgcn_mfma_f32_32x32x16_bf16(a0, b1, acc01, 0, 0, 0);
      acc10 = __builtin_amdgcn_mfma_f32_32x32x16_bf16(a1, b0, acc10, 0, 0, 0);
      acc11 = __builtin_amdgcn_mfma_f32_32x32x16_bf16(a1, b1, acc11, 0, 0, 0);
    }
    __syncthreads();
  }

  // epilogue: bias by boundary class, ReLU, bf16 store, stats
  float ls0 = 0.f, lss0 = 0.f, ls1 = 0.f, lss1 = 0.f;
  const int col0 = l31, col1 = 32 + l31;
#pragma unroll
  for (int mt = 0; mt < 2; ++mt) {
    const floatx16& aN0 = mt ? acc10 : acc00;
    const floatx16& aN1 = mt ? acc11 : acc01;
    const int rbb = m0 + mt * 32 + 4 * (lane >> 5);
#pragma unroll
    for (int r = 0; r < 16; ++r) {
      const int rw = rbb + (r & 3) + 8 * (r >> 2);
      if (rw < 196) {
        const int e_l = rw / 49, pr = rw % 49;
        const int ooy = pr / 7, oox = pr % 7;
        const int ry = (ooy == 0) ? 1 : 0;   // Hin=14 even: no bottom clip
        const int rx = (oox == 0) ? 1 : 0;
        const int cls = ry * 3 + rx;
        const size_t ob = ((size_t)(b * 64 + e0 + e_l) * 49 + pr) * 64;
        const float v0 = fmaxf(aN0[r] + biasS[cls * 64 + col0], 0.f);
        const float v1 = fmaxf(aN1[r] + biasS[cls * 64 + col1], 0.f);
        y2[ob + col0] = f2bf(v0);
        y2[ob + col1] = f2bf(v1);
        ls0 += v0; lss0 = fmaf(v0, v0, lss0);
        ls1 += v1; lss1 = fmaf(v1, v1, lss1);
      }
    }
  }
  atomicAdd(&redsum[col0], ls0);
  atomicAdd(&redss[col0], lss0);
  atomicAdd(&redsum[col1], ls1);
  atomicAdd(&redss[col1], lss1);
  __syncthreads();
  if (tid < 64) {
    const int sh = blockIdx.x & (NSHARD - 1);
    atomicAdd(&statsSh[sh * 128 + tid], redsum[tid]);
    atomicAdd(&statsSh[sh * 128 + 64 + tid], redss[tid]);
  }
}

// ---------------------------------------------------------------------------
// conv_core_bn: layers 3..4.  Reduce prev stats -> (s,t); stage G-image map
// once with BN folded in (zero-row = exact ref zero-padding); B from global
// (L2); plain ReLU epilogue; sharded stats.  [R10-proven]
// ---------------------------------------------------------------------------
template <int Hin, int Hout, int G>
__device__ __forceinline__ void conv_core_bn(
    const u16* __restrict__ yin, const u16* __restrict__ wT,
    const float* __restrict__ statsPrev, float invN, u16* __restrict__ yout,
    float* __restrict__ statsSh, int blk)
{
  constexpr int PPI  = Hout * Hout;
  constexpr int ROWS = G * PPI;          // <= 64
  constexpr int BPT  = 64 / G;
  constexpr int MR   = G * Hin * Hin;
  constexpr int ZR   = MR;

  __shared__ __align__(16) u16 mapS[(MR + 1) * 72];
  __shared__ float P[256];
  __shared__ float s1[64], t1[64];
  __shared__ float redsum[64], redss[64];

  const int b = blk / BPT, e0 = (blk % BPT) * G;
  const int tid = threadIdx.x, lane = tid & 63, wave = tid >> 6;

  if (tid < 64) { redsum[tid] = 0.f; redss[tid] = 0.f; }
  if (tid < 9) *(uint4*)&mapS[ZR * 72 + tid * 8] = uint4{0, 0, 0, 0};
  {
    const int cidx = tid & 127, g = tid >> 7;
    float a = 0.f;
    for (int k = 0; k < NSHARD / 2; ++k)
      a += statsPrev[(g * (NSHARD / 2) + k) * 128 + cidx];
    P[tid] = a;
  }
  __syncthreads();
  if (tid < 64) {
    const float m = (P[tid] + P[tid + 128]) * invN;
    const float var = fmaf(-m, m, (P[64 + tid] + P[192 + tid]) * invN);
    const float s = rsqrtf(var + BN_EPS);
    s1[tid] = s;
    t1[tid] = -m * s;
  }
  __syncthreads();

  {
    const u16* src = yin + (size_t)(b * 64 + e0) * (Hin * Hin) * 64;
    for (int ch = tid; ch < MR * 8; ch += 256) {
      const int r = ch >> 3, c0 = (ch & 7) * 8;
      uint4 v = *(const uint4*)(src + ch * 8);
      const u16* h = (const u16*)&v;
      alignas(16) u16 o[8];
#pragma unroll
      for (int j = 0; j < 8; ++j)
        o[j] = f2bf(fmaf(bf2f(h[j]), s1[c0 + j], t1[c0 + j]));
      *(uint4*)&mapS[r * 72 + c0] = *(uint4*)o;
    }
  }

  const int m0 = (wave & 1) * 32, n0 = (wave >> 1) * 32;
  const int l31 = lane & 31, kq8 = (lane >> 5) * 8;
  const int lrow = m0 + l31;
  const bool rv = lrow < ROWS;
  const int img = rv ? lrow / PPI : 0;
  const int pp  = rv ? lrow % PPI : 0;
  const int oy = pp / Hout, ox = pp % Hout;
  const u16* wbB = wT + (size_t)b * 9 * 4096 + (n0 + l31) * 64 + kq8;

  floatx16 acc;
#pragma unroll
  for (int r = 0; r < 16; ++r) acc[r] = 0.f;

  __syncthreads();   // map ready

#pragma unroll
  for (int s = 0; s < 9; ++s) {
    const int ky = s / 3, kx = s % 3;
    int pix = ZR;
    if (rv) {
      const int iy = 2 * oy - 1 + ky, ix = 2 * ox - 1 + kx;
      if ((unsigned)iy < (unsigned)Hin && (unsigned)ix < (unsigned)Hin)
        pix = img * (Hin * Hin) + iy * Hin + ix;
    }
    const u16* ap = &mapS[pix * 72 + kq8];
    const u16* bp = wbB + s * 4096;
#pragma unroll
    for (int kk = 0; kk < 4; ++kk) {
      bf16x8 a  = *(const bf16x8*)(ap + kk * 16);
      bf16x8 bv = *(const bf16x8*)(bp + kk * 16);
      acc = __builtin_amdgcn_mfma_f32_32x32x16_bf16(a, bv, acc, 0, 0, 0);
    }
  }

  const int col = n0 + l31;
  const int rb = m0 + 4 * (lane >> 5);
  float ls = 0.f, lss = 0.f;
#pragma unroll
  for (int r = 0; r < 16; ++r) {
    const int rw = rb + (r & 3) + 8 * (r >> 2);
    if (rw < ROWS) {
      const int re = rw / PPI, pr = rw % PPI;
      const float v = fmaxf(acc[r], 0.f);
      yout[((size_t)(b * 64 + e0 + re) * PPI + pr) * 64 + col] = f2bf(v);
      ls += v;
      lss = fmaf(v, v, lss);
    }
  }
  atomicAdd(&redsum[col], ls);
  atomicAdd(&redss[col], lss);
  __syncthreads();
  if (tid < 64) {
    const int sh = blk & (NSHARD - 1);
    atomicAdd(&statsSh[sh * 128 + tid], redsum[tid]);
    atomicAdd(&statsSh[sh * 128 + 64 + tid], redss[tid]);
  }
}

__global__ __launch_bounds__(256) void cg3_k(
    const u16* __restrict__ yin, const u16* __restrict__ wT,
    const float* __restrict__ stPrev, float invN, u16* __restrict__ yout,
    float* __restrict__ statsSh) {
  conv_core_bn<7, 4, 4>(yin, wT, stPrev, invN, yout, statsSh, blockIdx.x);
}
__global__ __launch_bounds__(256) void cg4_k(
    const u16* __restrict__ yin, const u16* __restrict__ wT,
    const float* __restrict__ stPrev, float invN, u16* __restrict__ yout,
    float* __restrict__ statsSh) {
  conv_core_bn<4, 2, 16>(yin, wT, stPrev, invN, yout, statsSh, blockIdx.x);
}

// ---------------------------------------------------------------------------
// readout: reduce st4 shards, feat = BN(maxpool(y4)), out = feat @ w_ro[b].
// ---------------------------------------------------------------------------
__global__ __launch_bounds__(256) void readout_k(
    const u16* __restrict__ y4, const float* __restrict__ w_ro,
    const float* __restrict__ statsSh, float invN, float* __restrict__ outp)
{
  __shared__ float wl[64 * 20];
  __shared__ float feat[64 * 64];
  __shared__ float P[256];
  __shared__ float sArr[64], tArr[64];

  const int b = blockIdx.x, tid = threadIdx.x;

  {
    const int g = tid >> 7, cidx = tid & 127;
    float acc = 0.f;
    for (int k = 0; k < NSHARD / 2; ++k)
      acc += statsSh[(g * (NSHARD / 2) + k) * 128 + cidx];
    P[tid] = acc;
  }
  for (int i = tid; i < 1280; i += 256) wl[i] = w_ro[(size_t)b * 1280 + i];
  __syncthreads();
  if (tid < 64) {
    const float m = (P[tid] + P[tid + 128]) * invN;
    const float var = fmaf(-m, m, (P[64 + tid] + P[192 + tid]) * invN);
    const float s = rsqrtf(var + BN_EPS);
    sArr[tid] = s;
    tArr[tid] = -m * s;
  }
  __syncthreads();

  {
    const int e = tid & 63;
    for (int c = tid >> 6; c < 64; c += 4) {
      const u16* p4 = y4 + ((size_t)(b * 64 + e) * 4) * 64 + c;
      const float v = fmaxf(fmaxf(bf2f(p4[0]), bf2f(p4[64])),
                            fmaxf(bf2f(p4[128]), bf2f(p4[192])));
      feat[c * 64 + e] = fmaf(v, sArr[c], tArr[c]);
    }
  }
  __syncthreads();

  const int e = tid >> 2, og = (tid & 3) * 5;
  float acc[5] = {0.f, 0.f, 0.f, 0.f, 0.f};
  for (int c = 0; c < 64; ++c) {
    const float f = feat[c * 64 + e];
#pragma unroll
    for (int j = 0; j < 5; ++j) acc[j] = fmaf(f, wl[c * 20 + og + j], acc[j]);
  }
#pragma unroll
  for (int j = 0; j < 5; ++j)
    outp[((size_t)b * 64 + e) * 20 + og + j] = acc[j];
}

// ---------------------------------------------------------------------------
extern "C" void kernel_launch(void* const* d_in, const int* in_sizes, int n_in,
                              void* d_out, int out_size, void* d_ws, size_t ws_size,
                              hipStream_t stream) {
  (void)in_sizes; (void)n_in; (void)out_size; (void)ws_size;
  const float* x   = (const float*)d_in[0];
  const float* k1  = (const float*)d_in[1];
  const float* k2  = (const float*)d_in[2];
  const float* k3  = (const float*)d_in[3];
  const float* k4  = (const float*)d_in[4];
  const float* wro = (const float*)d_in[5];
  float* out = (float*)d_out;
  char* ws = (char*)d_ws;

  // ws layout (bytes), total ~136.3 MB:
  //  stats: 4 x 64 shards x 128 f32      @ 0          (131072)
  //  bias2: 64 x 576 f32                 @ 131072     (147456)  [memset w/ stats]
  //  k2f   bf16 (BN-folded)              @ 278528     (4718592)
  //  k3T/k4T bf16 (plain transpose)      @ 4997120 / 9715712
  //  y2 bf16 [4096][49][64]              @ 14434304   (25690112)
  //  y1 bf16 [4096][196][64]             @ 40124416   (102760448)
  //  y3/y4 alias into y1 (dead after cg2)
  float* stats = (float*)ws;
  float* bias2 = (float*)(ws + 131072);
  u16* k2f = (u16*)(ws + 278528);
  u16* k3T = (u16*)(ws + 4997120);
  u16* k4T = (u16*)(ws + 9715712);
  u16* y2  = (u16*)(ws + 14434304);
  u16* y1  = (u16*)(ws + 40124416);
  u16* y3  = y1;
  u16* y4  = y3 + (size_t)4194304;

  float* st1 = stats;
  float* st2 = stats + 8192;
  float* st3 = stats + 16384;
  float* st4 = stats + 24576;

  hipMemsetAsync(stats, 0, 131072 + 147456, stream);

  c1_k<<<4224, 256, 0, stream>>>(x, k1, k3, k4, k3T, k4T, y1, st1);
  foldw_k<<<192, 256, 0, stream>>>(k2, st1, 1.f / 802816.f, k2f, bias2);
  cg2_k<<<1024, 256, 0, stream>>>(y1, k2f, bias2, y2, st2);
  cg3_k<<<1024, 256, 0, stream>>>(y2, k3T, st2, 1.f / 200704.f, y3, st3);
  cg4_k<<<256, 256, 0, stream>>>(y3, k4T, st3, 1.f / 65536.f, y4, st4);
  readout_k<<<64, 256, 0, stream>>>(y4, wro, st4, 1.f / 16384.f, out);
}